// Round 1
// baseline (215.642 us; speedup 1.0000x reference)
//
#include <hip/hip_runtime.h>
#include <hip/hip_bf16.h>
#include <math.h>

// Problem constants: B=8, M=256, N=256, I=64, O=64, NM=16
// Workspace float layout:
//   [0)      tabA  [kg=4][n=256][kl=4][2]   8192   forward-n twiddles (cos,-sin)
//   [8192)   twF   [g=8][m=256][kl=4][2]   16384   forward-m twiddles (cos,-sin)
//   [24576)  twI   [kx=32][m=256][2]       16384   inverse-m twiddles (cos,+sin)/256
//   [40960)  tabE  [f=32][n=256]            8192   inverse-n basis (scaled cos / -sin)
//   [49152)  Wf    [o'=64][o=64]            4096   I + lin_w
//   [65536)  T     [b=8][ky=16][m=256][i=64][2]   = 4194304
//   [+T]     X     [b=8][ky=16][kx=32][i=64][2]   =  524288
//   [+X]     Y2    [b=8][kx=32][ky=16][o=64][2]   =  524288
//   [+Y2]    G     [b=8][m=256][ky=16][o=64][2]   = 4194304
// end = 9,502,720 floats = 36.25 MiB

#define TOFF  65536
#define XOFF  (TOFF + 4194304)
#define YOFF  (XOFF + 524288)
#define GOFF  (YOFF + 524288)

__global__ __launch_bounds__(256) void setup_tables(const float* __restrict__ lin_w,
                                                    float* __restrict__ ws) {
    int j = blockIdx.x * 256 + threadIdx.x;
    const float ANG = 0.024543692606170259f; // 2*pi/256
    if (j < 4096) {                       // tabA
        int n = j >> 4, ky = j & 15;
        int a = (n * ky) & 255;
        float s, c; sincosf(ANG * (float)a, &s, &c);
        int kg = ky >> 2, kl = ky & 3;
        float* p = ws + kg * 2048 + n * 8 + kl * 2;
        p[0] = c; p[1] = -s;
    } else if (j < 12288) {               // twF
        int e = j - 4096; int m = e >> 5, kx = e & 31;
        int kxe = kx + (kx < 16 ? 0 : 224);   // 0..15, 240..255
        int a = (m * kxe) & 255;
        float s, c; sincosf(ANG * (float)a, &s, &c);
        int g = kx >> 2, kl = kx & 3;
        float* p = ws + 8192 + g * 2048 + m * 8 + kl * 2;
        p[0] = c; p[1] = -s;
    } else if (j < 20480) {               // twI
        int e = j - 12288; int kx = e >> 8, m = e & 255;
        int kxe = kx + (kx < 16 ? 0 : 224);
        int a = (kxe * m) & 255;
        float s, c; sincosf(ANG * (float)a, &s, &c);
        float* p = ws + 24576 + (kx * 256 + m) * 2;
        p[0] = c * (1.0f / 256.0f);
        p[1] = s * (1.0f / 256.0f);
    } else if (j < 28672) {               // tabE
        int e = j - 20480; int f = e >> 8, n = e & 255;
        int ky = f >> 1, h = f & 1;
        int a = (ky * n) & 255;
        float s, c; sincosf(ANG * (float)a, &s, &c);
        float scale = (ky == 0 ? 1.0f : 2.0f) * (1.0f / 256.0f);
        ws[40960 + f * 256 + n] = h ? (-scale * s) : (scale * c);
    } else if (j < 32768) {               // Wf = I + lin_w
        int e = j - 28672;
        int op = e >> 6, o = e & 63;
        ws[49152 + e] = lin_w[e] + ((op == o) ? 1.0f : 0.0f);
    }
}

// Stage A: per (b,m): T[ky,i] = sum_n x[n,i] * (cos - i sin)(2pi ky n/256)
__global__ __launch_bounds__(256) void stageA(const float* __restrict__ x,
                                              const float* __restrict__ tabA,
                                              float* __restrict__ T) {
    __shared__ float xs[256 * 64];  // 64 KiB [n][i]
    int bid = blockIdx.x;           // b*256 + m
    int b = bid >> 8, m = bid & 255;
    int t = threadIdx.x;
    const float4* xg4 = (const float4*)(x + (size_t)bid * 256 * 64);
    float4* xs4 = (float4*)xs;
#pragma unroll
    for (int q = 0; q < 16; ++q) xs4[t + q * 256] = xg4[t + q * 256];
    __syncthreads();
    int i = t & 63, kg = t >> 6;
    const float* tw = tabA + __builtin_amdgcn_readfirstlane(kg * 2048);
    float aR0 = 0, aR1 = 0, aR2 = 0, aR3 = 0;
    float aI0 = 0, aI1 = 0, aI2 = 0, aI3 = 0;
#pragma unroll 4
    for (int n = 0; n < 256; ++n) {
        float xv = xs[n * 64 + i];
        const float* tp = tw + n * 8;
        aR0 = fmaf(tp[0], xv, aR0); aI0 = fmaf(tp[1], xv, aI0);
        aR1 = fmaf(tp[2], xv, aR1); aI1 = fmaf(tp[3], xv, aI1);
        aR2 = fmaf(tp[4], xv, aR2); aI2 = fmaf(tp[5], xv, aI2);
        aR3 = fmaf(tp[6], xv, aR3); aI3 = fmaf(tp[7], xv, aI3);
    }
    int ky0 = kg * 4;
    float2* Tb = (float2*)T;
    Tb[((size_t)(b * 16 + ky0 + 0) * 256 + m) * 64 + i] = make_float2(aR0, aI0);
    Tb[((size_t)(b * 16 + ky0 + 1) * 256 + m) * 64 + i] = make_float2(aR1, aI1);
    Tb[((size_t)(b * 16 + ky0 + 2) * 256 + m) * 64 + i] = make_float2(aR2, aI2);
    Tb[((size_t)(b * 16 + ky0 + 3) * 256 + m) * 64 + i] = make_float2(aR3, aI3);
}

// Stage B: X[kx,ky,i] = sum_m T[m,ky,i] * twF[kx,m]
__global__ __launch_bounds__(256) void stageB(const float* __restrict__ T,
                                              const float* __restrict__ twF,
                                              float* __restrict__ X) {
    int bid = blockIdx.x;            // b*32 + ky*2 + half
    int b = bid >> 5;
    int ky = (bid >> 1) & 15;
    int half = bid & 1;
    int t = threadIdx.x, i = t & 63, kg = t >> 6;
    int g = half * 4 + kg;           // 0..7 group of 4 kx
    const float2* Tp = (const float2*)T + (size_t)(b * 16 + ky) * 256 * 64 + i;
    const float* tw = twF + __builtin_amdgcn_readfirstlane(g * 2048);
    float r0 = 0, r1 = 0, r2 = 0, r3 = 0;
    float q0 = 0, q1 = 0, q2 = 0, q3 = 0;
#pragma unroll 4
    for (int m = 0; m < 256; ++m) {
        float2 tv = Tp[(size_t)m * 64];
        const float* tp = tw + m * 8;
        r0 = fmaf(tv.x, tp[0], fmaf(-tv.y, tp[1], r0));
        q0 = fmaf(tv.x, tp[1], fmaf( tv.y, tp[0], q0));
        r1 = fmaf(tv.x, tp[2], fmaf(-tv.y, tp[3], r1));
        q1 = fmaf(tv.x, tp[3], fmaf( tv.y, tp[2], q1));
        r2 = fmaf(tv.x, tp[4], fmaf(-tv.y, tp[5], r2));
        q2 = fmaf(tv.x, tp[5], fmaf( tv.y, tp[4], q2));
        r3 = fmaf(tv.x, tp[6], fmaf(-tv.y, tp[7], r3));
        q3 = fmaf(tv.x, tp[7], fmaf( tv.y, tp[6], q3));
    }
    int kx0 = g * 4;
    float2* Xb = (float2*)X;
    size_t base = ((size_t)(b * 16 + ky) * 32 + kx0) * 64 + i;
    Xb[base + 0 * 64] = make_float2(r0, q0);
    Xb[base + 1 * 64] = make_float2(r1, q1);
    Xb[base + 2 * 64] = make_float2(r2, q2);
    Xb[base + 3 * 64] = make_float2(r3, q3);
}

// Stage C: per (kx,ky): Y[b,o'] = sum_i X[b,i]*W[i,o'];  Y2[b,o] = sum_o' Y[b,o']*Wf[o',o]
__global__ __launch_bounds__(256) void stageC(const float* __restrict__ Xg,
                                              const float* __restrict__ w1,
                                              const float* __restrict__ w2,
                                              const float* __restrict__ Wf,
                                              float* __restrict__ Y2) {
    __shared__ float Ws[64 * 64 * 2];  // 32 KiB [i][o][2]
    __shared__ float Xs[8 * 64 * 2];   //  4 KiB [b][i][2]
    __shared__ float Ys[8 * 64 * 2];   //  4 KiB [b][o][2]
    __shared__ float Wfs[64 * 64];     // 16 KiB
    int bid = blockIdx.x;              // ky*32 + kx  (kx-major for XCD/L2 reuse of W lines)
    int kx = bid & 31, ky = bid >> 5;
    int t = threadIdx.x;
    const float* wsrc = (kx < 16) ? w1 : w2;
    int xx = kx & 15;
#pragma unroll
    for (int q = 0; q < 16; ++q) {
        int p = t + q * 256;
        int ii = p >> 6, oo = p & 63;
        float2 wv = *(const float2*)(wsrc + ((size_t)(ii * 64 + oo) * 256 + xx * 16 + ky) * 2);
        ((float2*)Ws)[ii * 64 + oo] = wv;
    }
#pragma unroll
    for (int q = 0; q < 2; ++q) {
        int p = t + q * 256;
        int bb = p >> 6, ii = p & 63;
        ((float2*)Xs)[bb * 64 + ii] =
            ((const float2*)Xg)[((size_t)(bb * 16 + ky) * 32 + kx) * 64 + ii];
    }
#pragma unroll
    for (int q = 0; q < 16; ++q) Wfs[t + q * 256] = Wf[t + q * 256];
    __syncthreads();
    int o = t & 63, bg = t >> 6;
    float yr0 = 0, yi0 = 0, yr1 = 0, yi1 = 0;
    for (int ii = 0; ii < 64; ++ii) {
        float2 w = ((float2*)Ws)[ii * 64 + o];
        float2 xa = ((float2*)Xs)[bg * 64 + ii];
        float2 xb = ((float2*)Xs)[(bg + 4) * 64 + ii];
        yr0 = fmaf(xa.x, w.x, fmaf(-xa.y, w.y, yr0));
        yi0 = fmaf(xa.x, w.y, fmaf( xa.y, w.x, yi0));
        yr1 = fmaf(xb.x, w.x, fmaf(-xb.y, w.y, yr1));
        yi1 = fmaf(xb.x, w.y, fmaf( xb.y, w.x, yi1));
    }
    ((float2*)Ys)[bg * 64 + o] = make_float2(yr0, yi0);
    ((float2*)Ys)[(bg + 4) * 64 + o] = make_float2(yr1, yi1);
    __syncthreads();
    float zr0 = 0, zi0 = 0, zr1 = 0, zi1 = 0;
    for (int op = 0; op < 64; ++op) {
        float wf = Wfs[op * 64 + o];
        float2 ya = ((float2*)Ys)[bg * 64 + op];
        float2 yb = ((float2*)Ys)[(bg + 4) * 64 + op];
        zr0 = fmaf(ya.x, wf, zr0); zi0 = fmaf(ya.y, wf, zi0);
        zr1 = fmaf(yb.x, wf, zr1); zi1 = fmaf(yb.y, wf, zi1);
    }
    float2* Yb = (float2*)Y2;
    Yb[((size_t)(bg * 32 + kx) * 16 + ky) * 64 + o] = make_float2(zr0, zi0);
    Yb[((size_t)((bg + 4) * 32 + kx) * 16 + ky) * 64 + o] = make_float2(zr1, zi1);
}

// Stage D: G[m,ky,o] = sum_kx Y2[kx,ky,o] * twI[kx,m]
__global__ __launch_bounds__(512) void stageD(const float* __restrict__ Y2,
                                              const float* __restrict__ twI,
                                              float* __restrict__ G) {
    __shared__ float Ysl[16 * 64 * 2];  // 8 KiB slice [ky][o][2]
    int bid = blockIdx.x;               // b*32 + mg
    int b = bid >> 5, mg = bid & 31;
    int t = threadIdx.x, o = t & 63, ml = t >> 6;   // 8 m per block, 1 per thread
    int m = mg * 8 + ml;
    float gr[16], gi[16];
#pragma unroll
    for (int k = 0; k < 16; ++k) { gr[k] = 0.f; gi[k] = 0.f; }
    for (int kx = 0; kx < 32; ++kx) {
        __syncthreads();
        const float2* src = (const float2*)Y2 + (size_t)(b * 32 + kx) * 1024;
#pragma unroll
        for (int q = 0; q < 2; ++q) ((float2*)Ysl)[t + q * 512] = src[t + q * 512];
        __syncthreads();
        int off = __builtin_amdgcn_readfirstlane((kx * 256 + m) * 2);
        float c = twI[off], d = twI[off + 1];
#pragma unroll
        for (int ky = 0; ky < 16; ++ky) {
            float2 yv = ((float2*)Ysl)[ky * 64 + o];
            gr[ky] = fmaf(yv.x, c, fmaf(-yv.y, d, gr[ky]));
            gi[ky] = fmaf(yv.x, d, fmaf( yv.y, c, gi[ky]));
        }
    }
    float2* Gb = (float2*)G;
#pragma unroll
    for (int ky = 0; ky < 16; ++ky)
        Gb[((size_t)(b * 256 + m) * 16 + ky) * 64 + o] = make_float2(gr[ky], gi[ky]);
}

// Stage E: per (b,m): out[n,o] = relu( sum_f Bas[f,n]*H[f,o] + lin_b[o] )
__global__ __launch_bounds__(256) void stageE(const float* __restrict__ G,
                                              const float* __restrict__ tabE,
                                              const float* __restrict__ lin_b,
                                              float* __restrict__ out) {
    __shared__ float Bs[32 * 256];  // 32 KiB [f][n]
    __shared__ float Hs[32 * 64];   //  8 KiB [f][o]
    int bid = blockIdx.x;           // b*256 + m
    int t = threadIdx.x;
    const float4* tE4 = (const float4*)tabE;
#pragma unroll
    for (int q = 0; q < 8; ++q) ((float4*)Bs)[t + q * 256] = tE4[t + q * 256];
    const float2* Gp = (const float2*)G + (size_t)bid * 1024;
#pragma unroll
    for (int q = 0; q < 4; ++q) {
        int p = t + q * 256;
        int ky = p >> 6, o = p & 63;
        float2 g = Gp[p];
        Hs[(2 * ky) * 64 + o] = g.x;
        Hs[(2 * ky + 1) * 64 + o] = g.y;
    }
    __syncthreads();
    int o4 = (t & 15) * 4, n0 = (t >> 4) * 16;
    float acc[16][4];
#pragma unroll
    for (int j = 0; j < 16; ++j) { acc[j][0] = acc[j][1] = acc[j][2] = acc[j][3] = 0.f; }
    for (int f = 0; f < 32; ++f) {
        float4 h = *(const float4*)(Hs + f * 64 + o4);
        const float* bp = Bs + f * 256 + n0;
        float4 a0 = *(const float4*)(bp);
        float4 a1 = *(const float4*)(bp + 4);
        float4 a2 = *(const float4*)(bp + 8);
        float4 a3 = *(const float4*)(bp + 12);
        float av[16] = {a0.x, a0.y, a0.z, a0.w, a1.x, a1.y, a1.z, a1.w,
                        a2.x, a2.y, a2.z, a2.w, a3.x, a3.y, a3.z, a3.w};
#pragma unroll
        for (int j = 0; j < 16; ++j) {
            acc[j][0] = fmaf(av[j], h.x, acc[j][0]);
            acc[j][1] = fmaf(av[j], h.y, acc[j][1]);
            acc[j][2] = fmaf(av[j], h.z, acc[j][2]);
            acc[j][3] = fmaf(av[j], h.w, acc[j][3]);
        }
    }
    float4 bias = *(const float4*)(lin_b + o4);
    float* outp = out + (size_t)bid * 256 * 64;
#pragma unroll
    for (int j = 0; j < 16; ++j) {
        int n = n0 + j;
        float4 r;
        r.x = fmaxf(acc[j][0] + bias.x, 0.f);
        r.y = fmaxf(acc[j][1] + bias.y, 0.f);
        r.z = fmaxf(acc[j][2] + bias.z, 0.f);
        r.w = fmaxf(acc[j][3] + bias.w, 0.f);
        *(float4*)(outp + (size_t)n * 64 + o4) = r;
    }
}

extern "C" void kernel_launch(void* const* d_in, const int* in_sizes, int n_in,
                              void* d_out, int out_size, void* d_ws, size_t ws_size,
                              hipStream_t stream) {
    const float* x     = (const float*)d_in[0];
    const float* w1    = (const float*)d_in[1];
    const float* w2    = (const float*)d_in[2];
    const float* lin_w = (const float*)d_in[3];
    const float* lin_b = (const float*)d_in[4];
    float* ws  = (float*)d_ws;
    float* out = (float*)d_out;

    float* T  = ws + TOFF;
    float* X  = ws + XOFF;
    float* Y2 = ws + YOFF;
    float* G  = ws + GOFF;

    setup_tables<<<128, 256, 0, stream>>>(lin_w, ws);
    stageA<<<2048, 256, 0, stream>>>(x, ws, T);
    stageB<<<256, 256, 0, stream>>>(T, ws + 8192, X);
    stageC<<<512, 256, 0, stream>>>(X, w1, w2, ws + 49152, Y2);
    stageD<<<256, 512, 0, stream>>>(Y2, ws + 24576, G);
    stageE<<<2048, 256, 0, stream>>>(G, ws + 40960, lin_b, out);
}

// Round 2
// 154.968 us; speedup vs baseline: 1.3915x; 1.3915x over previous
//
#include <hip/hip_runtime.h>
#include <hip/hip_bf16.h>
#include <math.h>

// Problem constants: B=8, M=256, N=256, I=64, O=64, NM=16
// Workspace float layout:
//   [0)      tabA  [n=256][ky=16][2]        8192   forward-n twiddles (cos,-sin)
//   [8192)   twF   [g=8][m=256][kl=4][2]   16384   forward-m twiddles (cos,-sin)
//   [24576)  twI   [kx=32][m=256][2]       16384   inverse-m twiddles (cos,+sin)/256
//   [40960)  tabE  [f=32][n=256]            8192   inverse-n basis (scaled cos / -sin)
//   [49152)  Wf    [o'=64][o=64]            4096   I + lin_w
//   [65536)  T     [b=8][ky=16][m=256][i=64][2]   = 4194304
//   [+T]     X     [b=8][ky=16][kx=32][i=64][2]   =  524288
//   [+X]     Y2    [b=8][kx=32][ky=16][o=64][2]   =  524288
//   [+Y2]    G     [b=8][m=256][ky=16][o=64][2]   = 4194304

#define TOFF  65536
#define XOFF  (TOFF + 4194304)
#define YOFF  (XOFF + 524288)
#define GOFF  (YOFF + 524288)

__global__ __launch_bounds__(256) void setup_tables(const float* __restrict__ lin_w,
                                                    float* __restrict__ ws) {
    int j = blockIdx.x * 256 + threadIdx.x;
    const float ANG = 0.024543692606170259f; // 2*pi/256
    if (j < 4096) {                       // tabA [n][ky][2]
        int n = j >> 4, ky = j & 15;
        int a = (n * ky) & 255;
        float s, c; sincosf(ANG * (float)a, &s, &c);
        float* p = ws + n * 32 + ky * 2;
        p[0] = c; p[1] = -s;
    } else if (j < 12288) {               // twF
        int e = j - 4096; int m = e >> 5, kx = e & 31;
        int kxe = kx + (kx < 16 ? 0 : 224);   // 0..15, 240..255
        int a = (m * kxe) & 255;
        float s, c; sincosf(ANG * (float)a, &s, &c);
        int g = kx >> 2, kl = kx & 3;
        float* p = ws + 8192 + g * 2048 + m * 8 + kl * 2;
        p[0] = c; p[1] = -s;
    } else if (j < 20480) {               // twI
        int e = j - 12288; int kx = e >> 8, m = e & 255;
        int kxe = kx + (kx < 16 ? 0 : 224);
        int a = (kxe * m) & 255;
        float s, c; sincosf(ANG * (float)a, &s, &c);
        float* p = ws + 24576 + (kx * 256 + m) * 2;
        p[0] = c * (1.0f / 256.0f);
        p[1] = s * (1.0f / 256.0f);
    } else if (j < 28672) {               // tabE
        int e = j - 20480; int f = e >> 8, n = e & 255;
        int ky = f >> 1, h = f & 1;
        int a = (ky * n) & 255;
        float s, c; sincosf(ANG * (float)a, &s, &c);
        float scale = (ky == 0 ? 1.0f : 2.0f) * (1.0f / 256.0f);
        ws[40960 + f * 256 + n] = h ? (-scale * s) : (scale * c);
    } else if (j < 32768) {               // Wf = I + lin_w
        int e = j - 28672;
        int op = e >> 6, o = e & 63;
        ws[49152 + e] = lin_w[e] + ((op == o) ? 1.0f : 0.0f);
    }
}

// Stage A v2: block = (b,m); wave w handles n in [64w, 64w+64); lane = i.
// x loads coalesced from global (vmcnt); twiddles wave-uniform scalar loads
// (lgkmcnt) -> independent counters, deep pipelining. acc[16 ky] in VGPRs,
// cross-wave reduce via 32 KiB LDS.
__global__ __launch_bounds__(256) void stageA(const float* __restrict__ x,
                                              const float* __restrict__ tabA,
                                              float* __restrict__ T) {
    __shared__ float red[4 * 16 * 64 * 2];  // 32 KiB [w][ky][i][2]
    int bid = blockIdx.x;  // b*256 + m
    int b = bid >> 8, m = bid & 255;
    int t = threadIdx.x;
    int i = t & 63, w = t >> 6;
    const float* xp = x + (size_t)bid * 16384 + (size_t)w * 4096 + i;
    float accR[16], accI[16];
#pragma unroll
    for (int k = 0; k < 16; ++k) { accR[k] = 0.f; accI[k] = 0.f; }
    int tw0 = __builtin_amdgcn_readfirstlane(w * 64 * 32);
#pragma unroll 4
    for (int nn = 0; nn < 64; ++nn) {
        float xv = xp[nn * 64];
        const float* tp = tabA + tw0 + nn * 32;
#pragma unroll
        for (int k = 0; k < 16; ++k) {
            accR[k] = fmaf(tp[2 * k], xv, accR[k]);
            accI[k] = fmaf(tp[2 * k + 1], xv, accI[k]);
        }
    }
#pragma unroll
    for (int k = 0; k < 16; ++k) {
        red[(w * 16 + k) * 128 + i * 2]     = accR[k];
        red[(w * 16 + k) * 128 + i * 2 + 1] = accI[k];
    }
    __syncthreads();
    int ky = t >> 4, i0 = (t & 15) * 4;
    float4 s0 = make_float4(0, 0, 0, 0), s1 = make_float4(0, 0, 0, 0);
#pragma unroll
    for (int ww = 0; ww < 4; ++ww) {
        const float* rp = red + (ww * 16 + ky) * 128 + i0 * 2;
        float4 a = *(const float4*)rp;
        float4 bq = *(const float4*)(rp + 4);
        s0.x += a.x; s0.y += a.y; s0.z += a.z; s0.w += a.w;
        s1.x += bq.x; s1.y += bq.y; s1.z += bq.z; s1.w += bq.w;
    }
    float* Tf = T + (((size_t)(b * 16 + ky) * 256 + m) * 64 + i0) * 2;
    *(float4*)Tf = s0;
    *(float4*)(Tf + 4) = s1;
}

// Stage B: X[kx,ky,i] = sum_m T[m,ky,i] * twF[kx,m]
__global__ __launch_bounds__(256) void stageB(const float* __restrict__ T,
                                              const float* __restrict__ twF,
                                              float* __restrict__ X) {
    int bid = blockIdx.x;            // b*32 + ky*2 + half
    int b = bid >> 5;
    int ky = (bid >> 1) & 15;
    int half = bid & 1;
    int t = threadIdx.x, i = t & 63, kg = t >> 6;
    int g = half * 4 + kg;           // 0..7 group of 4 kx
    const float2* Tp = (const float2*)T + (size_t)(b * 16 + ky) * 256 * 64 + i;
    const float* tw = twF + __builtin_amdgcn_readfirstlane(g * 2048);
    float r0 = 0, r1 = 0, r2 = 0, r3 = 0;
    float q0 = 0, q1 = 0, q2 = 0, q3 = 0;
#pragma unroll 4
    for (int m = 0; m < 256; ++m) {
        float2 tv = Tp[(size_t)m * 64];
        const float* tp = tw + m * 8;
        r0 = fmaf(tv.x, tp[0], fmaf(-tv.y, tp[1], r0));
        q0 = fmaf(tv.x, tp[1], fmaf( tv.y, tp[0], q0));
        r1 = fmaf(tv.x, tp[2], fmaf(-tv.y, tp[3], r1));
        q1 = fmaf(tv.x, tp[3], fmaf( tv.y, tp[2], q1));
        r2 = fmaf(tv.x, tp[4], fmaf(-tv.y, tp[5], r2));
        q2 = fmaf(tv.x, tp[5], fmaf( tv.y, tp[4], q2));
        r3 = fmaf(tv.x, tp[6], fmaf(-tv.y, tp[7], r3));
        q3 = fmaf(tv.x, tp[7], fmaf( tv.y, tp[6], q3));
    }
    int kx0 = g * 4;
    float2* Xb = (float2*)X;
    size_t base = ((size_t)(b * 16 + ky) * 32 + kx0) * 64 + i;
    Xb[base + 0 * 64] = make_float2(r0, q0);
    Xb[base + 1 * 64] = make_float2(r1, q1);
    Xb[base + 2 * 64] = make_float2(r2, q2);
    Xb[base + 3 * 64] = make_float2(r3, q3);
}

// Stage C: per (kx,ky): Y[b,o'] = sum_i X[b,i]*W[i,o'];  Y2[b,o] = sum_o' Y[b,o']*Wf[o',o]
__global__ __launch_bounds__(256) void stageC(const float* __restrict__ Xg,
                                              const float* __restrict__ w1,
                                              const float* __restrict__ w2,
                                              const float* __restrict__ Wf,
                                              float* __restrict__ Y2) {
    __shared__ float Ws[64 * 64 * 2];  // 32 KiB [i][o][2]
    __shared__ float Xs[8 * 64 * 2];   //  4 KiB [b][i][2]
    __shared__ float Ys[8 * 64 * 2];   //  4 KiB [b][o][2]
    __shared__ float Wfs[64 * 64];     // 16 KiB
    int bid = blockIdx.x;              // ky*32 + kx
    int kx = bid & 31, ky = bid >> 5;
    int t = threadIdx.x;
    const float* wsrc = (kx < 16) ? w1 : w2;
    int xx = kx & 15;
#pragma unroll
    for (int q = 0; q < 16; ++q) {
        int p = t + q * 256;
        int ii = p >> 6, oo = p & 63;
        float2 wv = *(const float2*)(wsrc + ((size_t)(ii * 64 + oo) * 256 + xx * 16 + ky) * 2);
        ((float2*)Ws)[ii * 64 + oo] = wv;
    }
#pragma unroll
    for (int q = 0; q < 2; ++q) {
        int p = t + q * 256;
        int bb = p >> 6, ii = p & 63;
        ((float2*)Xs)[bb * 64 + ii] =
            ((const float2*)Xg)[((size_t)(bb * 16 + ky) * 32 + kx) * 64 + ii];
    }
#pragma unroll
    for (int q = 0; q < 16; ++q) Wfs[t + q * 256] = Wf[t + q * 256];
    __syncthreads();
    int o = t & 63, bg = t >> 6;
    float yr0 = 0, yi0 = 0, yr1 = 0, yi1 = 0;
    for (int ii = 0; ii < 64; ++ii) {
        float2 w = ((float2*)Ws)[ii * 64 + o];
        float2 xa = ((float2*)Xs)[bg * 64 + ii];
        float2 xb = ((float2*)Xs)[(bg + 4) * 64 + ii];
        yr0 = fmaf(xa.x, w.x, fmaf(-xa.y, w.y, yr0));
        yi0 = fmaf(xa.x, w.y, fmaf( xa.y, w.x, yi0));
        yr1 = fmaf(xb.x, w.x, fmaf(-xb.y, w.y, yr1));
        yi1 = fmaf(xb.x, w.y, fmaf( xb.y, w.x, yi1));
    }
    ((float2*)Ys)[bg * 64 + o] = make_float2(yr0, yi0);
    ((float2*)Ys)[(bg + 4) * 64 + o] = make_float2(yr1, yi1);
    __syncthreads();
    float zr0 = 0, zi0 = 0, zr1 = 0, zi1 = 0;
    for (int op = 0; op < 64; ++op) {
        float wf = Wfs[op * 64 + o];
        float2 ya = ((float2*)Ys)[bg * 64 + op];
        float2 yb = ((float2*)Ys)[(bg + 4) * 64 + op];
        zr0 = fmaf(ya.x, wf, zr0); zi0 = fmaf(ya.y, wf, zi0);
        zr1 = fmaf(yb.x, wf, zr1); zi1 = fmaf(yb.y, wf, zi1);
    }
    float2* Yb = (float2*)Y2;
    Yb[((size_t)(bg * 32 + kx) * 16 + ky) * 64 + o] = make_float2(zr0, zi0);
    Yb[((size_t)((bg + 4) * 32 + kx) * 16 + ky) * 64 + o] = make_float2(zr1, zi1);
}

// Stage D: G[m,ky,o] = sum_kx Y2[kx,ky,o] * twI[kx,m]
__global__ __launch_bounds__(512) void stageD(const float* __restrict__ Y2,
                                              const float* __restrict__ twI,
                                              float* __restrict__ G) {
    __shared__ float Ysl[16 * 64 * 2];  // 8 KiB slice [ky][o][2]
    int bid = blockIdx.x;               // b*32 + mg
    int b = bid >> 5, mg = bid & 31;
    int t = threadIdx.x, o = t & 63, ml = t >> 6;   // 8 m per block
    int m = mg * 8 + ml;
    float gr[16], gi[16];
#pragma unroll
    for (int k = 0; k < 16; ++k) { gr[k] = 0.f; gi[k] = 0.f; }
    for (int kx = 0; kx < 32; ++kx) {
        __syncthreads();
        const float2* src = (const float2*)Y2 + (size_t)(b * 32 + kx) * 1024;
#pragma unroll
        for (int q = 0; q < 2; ++q) ((float2*)Ysl)[t + q * 512] = src[t + q * 512];
        __syncthreads();
        int off = __builtin_amdgcn_readfirstlane((kx * 256 + m) * 2);
        float c = twI[off], d = twI[off + 1];
#pragma unroll
        for (int ky = 0; ky < 16; ++ky) {
            float2 yv = ((float2*)Ysl)[ky * 64 + o];
            gr[ky] = fmaf(yv.x, c, fmaf(-yv.y, d, gr[ky]));
            gi[ky] = fmaf(yv.x, d, fmaf( yv.y, c, gi[ky]));
        }
    }
    float2* Gb = (float2*)G;
#pragma unroll
    for (int ky = 0; ky < 16; ++ky)
        Gb[((size_t)(b * 256 + m) * 16 + ky) * 64 + o] = make_float2(gr[ky], gi[ky]);
}

// Stage E: per (b,m): out[n,o] = relu( sum_f Bas[f,n]*H[f,o] + lin_b[o] )
__global__ __launch_bounds__(256) void stageE(const float* __restrict__ G,
                                              const float* __restrict__ tabE,
                                              const float* __restrict__ lin_b,
                                              float* __restrict__ out) {
    __shared__ float Bs[32 * 256];  // 32 KiB [f][n]
    __shared__ float Hs[32 * 64];   //  8 KiB [f][o]
    int bid = blockIdx.x;           // b*256 + m
    int t = threadIdx.x;
    const float4* tE4 = (const float4*)tabE;
#pragma unroll
    for (int q = 0; q < 8; ++q) ((float4*)Bs)[t + q * 256] = tE4[t + q * 256];
    const float2* Gp = (const float2*)G + (size_t)bid * 1024;
#pragma unroll
    for (int q = 0; q < 4; ++q) {
        int p = t + q * 256;
        int ky = p >> 6, o = p & 63;
        float2 g = Gp[p];
        Hs[(2 * ky) * 64 + o] = g.x;
        Hs[(2 * ky + 1) * 64 + o] = g.y;
    }
    __syncthreads();
    int o4 = (t & 15) * 4, n0 = (t >> 4) * 16;
    float acc[16][4];
#pragma unroll
    for (int j = 0; j < 16; ++j) { acc[j][0] = acc[j][1] = acc[j][2] = acc[j][3] = 0.f; }
    for (int f = 0; f < 32; ++f) {
        float4 h = *(const float4*)(Hs + f * 64 + o4);
        const float* bp = Bs + f * 256 + n0;
        float4 a0 = *(const float4*)(bp);
        float4 a1 = *(const float4*)(bp + 4);
        float4 a2 = *(const float4*)(bp + 8);
        float4 a3 = *(const float4*)(bp + 12);
        float av[16] = {a0.x, a0.y, a0.z, a0.w, a1.x, a1.y, a1.z, a1.w,
                        a2.x, a2.y, a2.z, a2.w, a3.x, a3.y, a3.z, a3.w};
#pragma unroll
        for (int j = 0; j < 16; ++j) {
            acc[j][0] = fmaf(av[j], h.x, acc[j][0]);
            acc[j][1] = fmaf(av[j], h.y, acc[j][1]);
            acc[j][2] = fmaf(av[j], h.z, acc[j][2]);
            acc[j][3] = fmaf(av[j], h.w, acc[j][3]);
        }
    }
    float4 bias = *(const float4*)(lin_b + o4);
    float* outp = out + (size_t)bid * 256 * 64;
#pragma unroll
    for (int j = 0; j < 16; ++j) {
        int n = n0 + j;
        float4 r;
        r.x = fmaxf(acc[j][0] + bias.x, 0.f);
        r.y = fmaxf(acc[j][1] + bias.y, 0.f);
        r.z = fmaxf(acc[j][2] + bias.z, 0.f);
        r.w = fmaxf(acc[j][3] + bias.w, 0.f);
        *(float4*)(outp + (size_t)n * 64 + o4) = r;
    }
}

extern "C" void kernel_launch(void* const* d_in, const int* in_sizes, int n_in,
                              void* d_out, int out_size, void* d_ws, size_t ws_size,
                              hipStream_t stream) {
    const float* x     = (const float*)d_in[0];
    const float* w1    = (const float*)d_in[1];
    const float* w2    = (const float*)d_in[2];
    const float* lin_w = (const float*)d_in[3];
    const float* lin_b = (const float*)d_in[4];
    float* ws  = (float*)d_ws;
    float* out = (float*)d_out;

    float* T  = ws + TOFF;
    float* X  = ws + XOFF;
    float* Y2 = ws + YOFF;
    float* G  = ws + GOFF;

    setup_tables<<<128, 256, 0, stream>>>(lin_w, ws);
    stageA<<<2048, 256, 0, stream>>>(x, ws, T);
    stageB<<<256, 256, 0, stream>>>(T, ws + 8192, X);
    stageC<<<512, 256, 0, stream>>>(X, w1, w2, ws + 49152, Y2);
    stageD<<<256, 512, 0, stream>>>(Y2, ws + 24576, G);
    stageE<<<2048, 256, 0, stream>>>(G, ws + 40960, lin_b, out);
}